// Round 10
// baseline (566.592 us; speedup 1.0000x reference)
//
#include <hip/hip_runtime.h>
#include <math.h>

#define ALPHA_SLOPE 0.2f

typedef _Float16 f16;
typedef f16 f16x4 __attribute__((ext_vector_type(4)));
typedef f16 f16x8 __attribute__((ext_vector_type(8)));
typedef float f32x4 __attribute__((ext_vector_type(4)));

constexpr int B_ = 8, N = 2048, D = 128, H = 2;
constexpr int C2 = H * D;           // 256
constexpr int M_ = B_ * N;          // 16384
constexpr int NCH = 32;             // scan chunks
constexpr int CHL = N / NCH;        // 64

__device__ __forceinline__ float lrelu(float x) { return fmaxf(x, ALPHA_SLOPE * x); }

// ---------- cvtW: W -> WcT f16, 128 blocks ----------
__global__ __launch_bounds__(256) void cvtW_kernel(
    const float* __restrict__ W00, const float* __restrict__ W01,
    const float* __restrict__ W10, const float* __restrict__ W11,
    f16* __restrict__ WcT)
{
    const int t = threadIdx.x;
    const int w = blockIdx.x;                  // [0,128)
#pragma unroll
    for (int p = 0; p < 4; ++p) {
        const int pair = w * 4 + p;            // [0,512)
        const int layer = pair >> 8, c = pair & 255;
        const float* __restrict__ W0 = layer ? W10 : W00;
        const float* __restrict__ W1 = layer ? W11 : W01;
        const float v = (c < D) ? W0[t * D + c] : W1[t * D + (c - D)];
        WcT[(size_t)layer * C2 * C2 + c * C2 + t] = (f16)v;
    }
}

// ---------- gemm_lr: 32-row tiles (512 blocks), inline fp32->f16 cvt for layer 0 ----------
__global__ __launch_bounds__(256) void gemm_lr_kernel(
    const float* __restrict__ x32, const f16* __restrict__ xh,
    const f16* __restrict__ Wl,
    const float* __restrict__ b0, const float* __restrict__ b1,
    const float* __restrict__ a0, const float* __restrict__ a1,
    f16* __restrict__ h,
    float* __restrict__ l0, float* __restrict__ r0,
    float* __restrict__ l1, float* __restrict__ r1,
    const int use32)
{
    __shared__ f16 hts[32][C2 + 8];   // 16896 B: x tile, then h tile
    const int t = threadIdx.x;
    const int row0 = blockIdx.x * 32;
    if (use32) {
#pragma unroll
        for (int p = 0; p < 8; ++p) {
            const int q = p * 256 + t;          // [0,2048) float4 units
            const int row = q >> 6, c4 = q & 63;
            const float4 v = *(const float4*)&x32[(size_t)(row0 + row) * C2 + c4 * 4];
            f16x4 o; o[0] = (f16)v.x; o[1] = (f16)v.y; o[2] = (f16)v.z; o[3] = (f16)v.w;
            *(f16x4*)&hts[row][c4 * 4] = o;
        }
    } else {
#pragma unroll
        for (int p = 0; p < 4; ++p) {
            const int q = p * 256 + t;          // [0,1024) f16x8 units
            const int row = q >> 5, cc = q & 31;
            *(f16x8*)&hts[row][cc * 8] = *(const f16x8*)&xh[(size_t)(row0 + row) * C2 + cc * 8];
        }
    }
    __syncthreads();
    const int w = t >> 6, l = t & 63;
    const int fm = l & 15, fk = (l >> 4) * 8;
    f32x4 acc[2][4] = {};
#pragma unroll
    for (int ks = 0; ks < 8; ++ks) {
        f16x8 af[2], bf[4];
#pragma unroll
        for (int rt = 0; rt < 2; ++rt)
            af[rt] = *(const f16x8*)&hts[rt * 16 + fm][ks * 32 + fk];
#pragma unroll
        for (int ct = 0; ct < 4; ++ct) {
            const int col = w * 64 + ct * 16 + fm;
            bf[ct] = *(const f16x8*)&Wl[(size_t)col * C2 + ks * 32 + fk];
        }
#pragma unroll
        for (int rt = 0; rt < 2; ++rt)
#pragma unroll
            for (int ct = 0; ct < 4; ++ct)
                acc[rt][ct] = __builtin_amdgcn_mfma_f32_16x16x32_f16(af[rt], bf[ct], acc[rt][ct], 0, 0, 0);
    }
    __syncthreads();   // x reads done; reuse as h tile (f16)
#pragma unroll
    for (int rt = 0; rt < 2; ++rt)
#pragma unroll
        for (int ct = 0; ct < 4; ++ct) {
            const int col = w * 64 + ct * 16 + fm;
            const float bias = (col < D) ? b0[col] : b1[col - D];
#pragma unroll
            for (int q = 0; q < 4; ++q) {
                const int row = rt * 16 + (l >> 4) * 4 + q;
                hts[row][col] = (f16)(acc[rt][ct][q] + bias);
            }
        }
    __syncthreads();
#pragma unroll
    for (int p = 0; p < 4; ++p) {
        const int q = p * 256 + t;
        const int row = q >> 5, cc = q & 31;
        *(f16x8*)&h[(size_t)(row0 + row) * C2 + cc * 8] = *(const f16x8*)&hts[row][cc * 8];
    }
    // l/r: 8 threads per row (oct), rotated cols to dodge bank conflicts
    const int lrow = t >> 3;
    const int oct = t & 7;
    const float* __restrict__ ab = (oct >= 4) ? a1 : a0;
    float lv = 0.f, rv = 0.f;
#pragma unroll
    for (int c4 = 0; c4 < 8; ++c4) {
        const int cc = (c4 + oct) & 7;
        const int col = oct * 32 + cc * 4;
        const int cih = (oct & 3) * 32 + cc * 4;
        const f16x4 hf = *(const f16x4*)&hts[lrow][col];
        const float4 alv = *(const float4*)&ab[cih];
        const float4 arv = *(const float4*)&ab[128 + cih];
        const float h0 = (float)hf[0], h1 = (float)hf[1], h2 = (float)hf[2], h3 = (float)hf[3];
        lv += h0 * alv.x + h1 * alv.y + h2 * alv.z + h3 * alv.w;
        rv += h0 * arv.x + h1 * arv.y + h2 * arv.z + h3 * arv.w;
    }
    lv += __shfl_xor(lv, 1, 64); lv += __shfl_xor(lv, 2, 64);
    rv += __shfl_xor(rv, 1, 64); rv += __shfl_xor(rv, 2, 64);
    const int grow = row0 + lrow;
    if (oct == 0) { l0[grow] = lv; r0[grow] = rv; }
    else if (oct == 4) { l1[grow] = lv; r1[grow] = rv; }
}

// ---------- rank: 1024-thread blocks, 16 wave-uniform j-chunks (full occupancy) ----------
__global__ __launch_bounds__(1024) void rank_kernel(
    const float* __restrict__ r0, const float* __restrict__ r1,
    const float* __restrict__ l0, const float* __restrict__ l1,
    float* __restrict__ rs_s, int* __restrict__ perm, int* __restrict__ kout)
{
    const int bh = blockIdx.y;
    const float* __restrict__ r = ((bh & 1) ? r1 : r0) + (size_t)(bh >> 1) * N;
    const float* __restrict__ lp = ((bh & 1) ? l1 : l0) + (size_t)(bh >> 1) * N;
    __shared__ float rl[N];
    __shared__ int scnt[16][64], sk2[16][64];
    const int t = threadIdx.x;
    for (int j = t; j < N; j += 1024) rl[j] = r[j];
    __syncthreads();
    const int el = t & 63;
    const int q = t >> 6;                       // wave index: j-chunk, uniform per wave
    const int e = blockIdx.x * 64 + el;
    const float re = rl[e];
    const float thr = -lp[e];
    const int qm = blockIdx.x >> 1;             // chunk containing this block's e's (128-wide)
    int cnt = 0, k2 = 0;
    const int jlo = q * 128, jhi = jlo + 128;
    if (q < qm) {
        for (int j = jlo; j < jhi; j += 4) {
            const float4 v = *(const float4*)&rl[j];
            cnt += (v.x >= re) + (v.y >= re) + (v.z >= re) + (v.w >= re);
            k2  += (v.x >= thr) + (v.y >= thr) + (v.z >= thr) + (v.w >= thr);
        }
    } else if (q > qm) {
        for (int j = jlo; j < jhi; j += 4) {
            const float4 v = *(const float4*)&rl[j];
            cnt += (v.x > re) + (v.y > re) + (v.z > re) + (v.w > re);
            k2  += (v.x >= thr) + (v.y >= thr) + (v.z >= thr) + (v.w >= thr);
        }
    } else {
        for (int j = jlo; j < jhi; j += 4) {
            const float4 v = *(const float4*)&rl[j];
            cnt += (v.x > re) || (v.x == re && (j + 0) < e);
            cnt += (v.y > re) || (v.y == re && (j + 1) < e);
            cnt += (v.z > re) || (v.z == re && (j + 2) < e);
            cnt += (v.w > re) || (v.w == re && (j + 3) < e);
            k2  += (v.x >= thr) + (v.y >= thr) + (v.z >= thr) + (v.w >= thr);
        }
    }
    scnt[q][el] = cnt; sk2[q][el] = k2;
    __syncthreads();
    if (t < 64) {
        int c = 0, kk = 0;
#pragma unroll
        for (int qq = 0; qq < 16; ++qq) { c += scnt[qq][t]; kk += sk2[qq][t]; }
        const int eg = blockIdx.x * 64 + t;
        const size_t g = (size_t)bh * N;
        rs_s[g + c] = rl[eg];
        perm[g + c] = eg;
        kout[g + eg] = kk;
    }
}

// ---------- scanA: per-chunk weights + local scalar scans + vector scans + totals ----------
__global__ __launch_bounds__(256) void scanA_kernel(
    const f16* __restrict__ h, const int* __restrict__ perm,
    const float* __restrict__ rs_s,
    f16* __restrict__ PA, f16* __restrict__ PB,
    float* __restrict__ SAloc, float* __restrict__ SBloc,
    float* __restrict__ totA, float* __restrict__ totB,
    float* __restrict__ stA, float* __restrict__ stB)
{
    __shared__ f16 hs[CHL][D];          // 16384 B
    __shared__ int pj[CHL];
    __shared__ float wA[CHL], wB[CHL];
    __shared__ float buf[2 * CHL];
    const int chunk = blockIdx.x, bh = blockIdx.y;
    const int b = bh >> 1, head = bh & 1;
    const int t = threadIdx.x;
    const size_t g = (size_t)bh * N + chunk * CHL;
    const float c1 = rs_s[(size_t)bh * N];
    if (t < CHL) {
        pj[t] = perm[g + t];
        const float rr = rs_s[g + t];
        const float eA = __expf(rr - c1);
        const float eB = __expf(0.2f * (rr - c1));
        wA[t] = eA; wB[t] = eB;
        buf[t] = eA;
    } else if (t < 2 * CHL) {
        const float rr = rs_s[g + (CHL - 1 - (t - CHL))];
        buf[t] = __expf(0.2f * (rr - c1));   // reversed B: suffix via prefix
    }
    __syncthreads();
    const int li = t & (CHL - 1);
#pragma unroll
    for (int off = 1; off < CHL; off <<= 1) {
        const float v = (t < 2 * CHL && li >= off) ? buf[t - off] : 0.f;
        __syncthreads();
        if (t < 2 * CHL && li >= off) buf[t] += v;
        __syncthreads();
    }
    if (t < CHL) SAloc[g + t] = buf[t];
    else if (t < 2 * CHL) SBloc[g + (CHL - 1 - li)] = buf[t];
    if (t == CHL - 1) stA[bh * NCH + chunk] = buf[CHL - 1];
    if (t == 2 * CHL - 1) stB[bh * NCH + chunk] = buf[2 * CHL - 1];
    // gather permuted h rows (f16)
#pragma unroll
    for (int p = 0; p < 4; ++p) {
        const int q = p * 256 + t;
        const int row = q >> 4, c8 = q & 15;
        const f16* src = h + (size_t)(b * N + pj[row]) * C2 + head * D;
        *(f16x8*)&hs[row][c8 * 8] = *(const f16x8*)&src[c8 * 8];
    }
    __syncthreads();
    if (t < D) {
        const int d = t;
        float acc = 0.f;
        for (int j = 0; j < CHL; ++j) {
            acc = fmaf(wA[j], (float)hs[j][d], acc);
            PA[(g + j) * D + d] = (f16)acc;
        }
        totA[(size_t)(bh * NCH + chunk) * D + d] = acc;
    } else {
        const int d = t - D;
        float acc = 0.f;
        for (int jj = 0; jj < CHL; ++jj) {
            const int j = CHL - 1 - jj;
            acc = fmaf(wB[j], (float)hs[j][d], acc);
            PB[(g + j) * D + d] = (f16)acc;
        }
        totB[(size_t)(bh * NCH + chunk) * D + d] = acc;
    }
}

// ---------- scanOff: per-bh chunk-offset exclusive scans ----------
__global__ __launch_bounds__(256) void scanOff_kernel(
    const float* __restrict__ totA, const float* __restrict__ totB,
    const float* __restrict__ stA, const float* __restrict__ stB,
    float* __restrict__ AOff, float* __restrict__ BOffS,
    float* __restrict__ lsAg, float* __restrict__ lsBg)
{
    const int bh = blockIdx.x;
    const int t = threadIdx.x;
    const size_t base = (size_t)bh * NCH;
    if (t < D) {
        const int d = t;
        float acc = 0.f;
#pragma unroll
        for (int ch = 0; ch < NCH; ++ch) {
            const float tmp = totA[(base + ch) * D + d];
            AOff[(base + ch) * D + d] = acc;
            acc += tmp;
        }
    } else {
        const int d = t - D;
        float acc = 0.f;
#pragma unroll
        for (int ch = NCH - 1; ch >= 0; --ch) {
            const float tmp = totB[(base + ch) * D + d];
            BOffS[(base + ch) * D + d] = acc;
            acc += tmp;
        }
    }
    if (t == 0) {
        float a = 0.f;
#pragma unroll
        for (int q = 0; q < NCH; ++q) { const float tmp = stA[base + q]; lsAg[base + q] = a; a += tmp; }
    } else if (t == 64) {
        float a = 0.f;
#pragma unroll
        for (int q = NCH - 1; q >= 0; --q) { const float tmp = stB[base + q]; lsBg[base + q] = a; a += tmp; }
    }
}

// ---------- out: LDS-free streaming combine + elu ----------
__global__ __launch_bounds__(256) void out_kernel(
    const f16* __restrict__ h,
    const float* __restrict__ l0v, const float* __restrict__ l1v,
    const float* __restrict__ r0v, const float* __restrict__ r1v,
    const int* __restrict__ perm, const float* __restrict__ rs_s,
    const int* __restrict__ kout,
    const float* __restrict__ SAloc, const float* __restrict__ SBloc,
    const float* __restrict__ lsAg, const float* __restrict__ lsBg,
    const float* __restrict__ AOff, const float* __restrict__ BOffS,
    const f16* __restrict__ PA, const f16* __restrict__ PB,
    float* __restrict__ out_f32, f16* __restrict__ out_f16, const int final_layer)
{
    const int head = blockIdx.y, b = blockIdx.z;
    const int bh = b * H + head;
    const float* __restrict__ lv = (head ? l1v : l0v) + (size_t)b * N;
    const float* __restrict__ rv = (head ? r1v : r0v) + (size_t)b * N;
    const int t = threadIdx.x;
    const size_t gb = (size_t)bh * N;
    const size_t obase = (size_t)bh * NCH;

    const int i = blockIdx.x * 16 + (t >> 4);
    const int c0 = (t & 15) * 8;
    const float li = lv[i];
    const float ri = rv[i];
    const float rmx1 = rs_s[gb];
    const float rmx2 = rs_s[gb + 1];
    const int rdx = perm[gb];
    const float rmx = (i == rdx) ? rmx2 : rmx1;
    const float m = lrelu(li + rmx);
    const float alpha = __expf(li + rmx1 - m);
    const float beta = __expf(0.2f * (li + rmx1) - m);
    const float diag = __expf(lrelu(li + ri) - m);

    const int k = kout[gb + i];
    const float SAk = (k > 0) ? (lsAg[obase + ((k - 1) >> 6)] + SAloc[gb + k - 1]) : 0.f;
    const float SBk = (k < N) ? (lsBg[obase + (k >> 6)] + SBloc[gb + k]) : 0.f;
    const float Z = fmaf(alpha, SAk, beta * SBk) - diag;
    const float invZ = 1.f / Z;

    float pa[8] = {}, pb[8] = {};
    if (k > 0) {
        const int kk = k - 1, ch = kk >> 6;
        const f16x8 v = *(const f16x8*)&PA[(gb + kk) * D + c0];
        const float4 o0 = *(const float4*)&AOff[(obase + ch) * D + c0];
        const float4 o1 = *(const float4*)&AOff[(obase + ch) * D + c0 + 4];
        pa[0] = (float)v[0] + o0.x; pa[1] = (float)v[1] + o0.y;
        pa[2] = (float)v[2] + o0.z; pa[3] = (float)v[3] + o0.w;
        pa[4] = (float)v[4] + o1.x; pa[5] = (float)v[5] + o1.y;
        pa[6] = (float)v[6] + o1.z; pa[7] = (float)v[7] + o1.w;
    }
    if (k < N) {
        const int ch = k >> 6;
        const f16x8 v = *(const f16x8*)&PB[(gb + k) * D + c0];
        const float4 o0 = *(const float4*)&BOffS[(obase + ch) * D + c0];
        const float4 o1 = *(const float4*)&BOffS[(obase + ch) * D + c0 + 4];
        pb[0] = (float)v[0] + o0.x; pb[1] = (float)v[1] + o0.y;
        pb[2] = (float)v[2] + o0.z; pb[3] = (float)v[3] + o0.w;
        pb[4] = (float)v[4] + o1.x; pb[5] = (float)v[5] + o1.y;
        pb[6] = (float)v[6] + o1.z; pb[7] = (float)v[7] + o1.w;
    }

    const f16x8 hraw = *(const f16x8*)&h[(size_t)(b * N + i) * C2 + head * D + c0];
    float o[8];
#pragma unroll
    for (int q = 0; q < 8; ++q) {
        const float hv = (float)hraw[q];
        const float num = alpha * pa[q] + beta * pb[q] - diag * hv;
        float v = fmaf(num, invZ, hv);
        o[q] = v > 0.f ? v : (__expf(v) - 1.f);
    }
    const size_t oidx = (size_t)(b * N + i) * C2 + head * D + c0;
    if (final_layer) {
        *(float4*)&out_f32[oidx] = make_float4(o[0], o[1], o[2], o[3]);
        *(float4*)&out_f32[oidx + 4] = make_float4(o[4], o[5], o[6], o[7]);
    } else {
        f16x8 ov;
#pragma unroll
        for (int q = 0; q < 8; ++q) ov[q] = (f16)o[q];
        *(f16x8*)&out_f16[oidx] = ov;
    }
}

extern "C" void kernel_launch(void* const* d_in, const int* in_sizes, int n_in,
                              void* d_out, int out_size, void* d_ws, size_t ws_size,
                              hipStream_t stream)
{
    float* ws = (float*)d_ws;
    size_t off = 0;
    f16* xh = (f16*)(ws + off);   off += (size_t)M_ * C2 / 2;
    f16* WcT = (f16*)(ws + off);  off += (size_t)C2 * C2;        // 2 layers f16
    f16* h = (f16*)(ws + off);    off += (size_t)M_ * C2 / 2;
    float* l0 = ws + off;         off += (size_t)B_ * N;
    float* r0 = ws + off;         off += (size_t)B_ * N;
    float* l1 = ws + off;         off += (size_t)B_ * N;
    float* r1 = ws + off;         off += (size_t)B_ * N;
    float* rs_s = ws + off;       off += (size_t)16 * N;
    int* perm = (int*)(ws + off); off += (size_t)16 * N;
    int* kout = (int*)(ws + off); off += (size_t)16 * N;
    float* SAloc = ws + off;      off += (size_t)16 * N;
    float* SBloc = ws + off;      off += (size_t)16 * N;
    f16* PA = (f16*)(ws + off);   off += (size_t)16 * N * D / 2;
    f16* PB = (f16*)(ws + off);   off += (size_t)16 * N * D / 2;
    float* totA = ws + off;       off += (size_t)16 * NCH * D;
    float* totB = ws + off;       off += (size_t)16 * NCH * D;
    float* stA = ws + off;        off += (size_t)16 * NCH;
    float* stB = ws + off;        off += (size_t)16 * NCH;
    float* AOff = ws + off;       off += (size_t)16 * NCH * D;
    float* BOffS = ws + off;      off += (size_t)16 * NCH * D;
    float* lsAg = ws + off;       off += (size_t)16 * NCH;
    float* lsBg = ws + off;       off += (size_t)16 * NCH;

    const float* x32 = (const float*)d_in[0];

    cvtW_kernel<<<128, 256, 0, stream>>>(
        (const float*)d_in[2], (const float*)d_in[5],
        (const float*)d_in[8], (const float*)d_in[11], WcT);

    for (int layer = 0; layer < 2; ++layer) {
        const int base = 2 + layer * 6;
        const float* b0 = (const float*)d_in[base + 1];
        const float* a0 = (const float*)d_in[base + 2];
        const float* b1 = (const float*)d_in[base + 4];
        const float* a1 = (const float*)d_in[base + 5];

        gemm_lr_kernel<<<M_ / 32, 256, 0, stream>>>(
            x32, xh, WcT + (size_t)layer * C2 * C2, b0, b1, a0, a1,
            h, l0, r0, l1, r1, layer == 0 ? 1 : 0);
        rank_kernel<<<dim3(N / 64, B_ * H), 1024, 0, stream>>>(
            r0, r1, l0, l1, rs_s, perm, kout);
        scanA_kernel<<<dim3(NCH, B_ * H), 256, 0, stream>>>(
            h, perm, rs_s, PA, PB, SAloc, SBloc, totA, totB, stA, stB);
        scanOff_kernel<<<B_ * H, 256, 0, stream>>>(
            totA, totB, stA, stB, AOff, BOffS, lsAg, lsBg);
        out_kernel<<<dim3(N / 16, H, B_), 256, 0, stream>>>(
            h, l0, l1, r0, r1, perm, rs_s, kout, SAloc, SBloc, lsAg, lsBg,
            AOff, BOffS, PA, PB, (float*)d_out, xh, layer == 1 ? 1 : 0);
    }

    // ===== diagnostic: 8 idempotent re-runs of the full layer-1 phase sequence =====
    // Measures in-situ marginal layer cost L (cold caches between phases, real gaps):
    // dur_us = 182 + 8L. All outputs rewrite identical values; absmax unchanged.
    {
        const float* b0 = (const float*)d_in[9];
        const float* a0 = (const float*)d_in[10];
        const float* b1 = (const float*)d_in[12];
        const float* a1 = (const float*)d_in[13];
        for (int rep = 0; rep < 8; ++rep) {
            gemm_lr_kernel<<<M_ / 32, 256, 0, stream>>>(
                x32, xh, WcT + (size_t)C2 * C2, b0, b1, a0, a1,
                h, l0, r0, l1, r1, 0);
            rank_kernel<<<dim3(N / 64, B_ * H), 1024, 0, stream>>>(
                r0, r1, l0, l1, rs_s, perm, kout);
            scanA_kernel<<<dim3(NCH, B_ * H), 256, 0, stream>>>(
                h, perm, rs_s, PA, PB, SAloc, SBloc, totA, totB, stA, stB);
            scanOff_kernel<<<B_ * H, 256, 0, stream>>>(
                totA, totB, stA, stB, AOff, BOffS, lsAg, lsBg);
            out_kernel<<<dim3(N / 16, H, B_), 256, 0, stream>>>(
                h, l0, l1, r0, r1, perm, rs_s, kout, SAloc, SBloc, lsAg, lsBg,
                AOff, BOffS, PA, PB, (float*)d_out, xh, 1);
        }
    }
}

// Round 11
// 181.363 us; speedup vs baseline: 3.1241x; 3.1241x over previous
//
#include <hip/hip_runtime.h>
#include <math.h>

#define ALPHA_SLOPE 0.2f

typedef _Float16 f16;
typedef f16 f16x4 __attribute__((ext_vector_type(4)));
typedef f16 f16x8 __attribute__((ext_vector_type(8)));
typedef float f32x4 __attribute__((ext_vector_type(4)));

constexpr int B_ = 8, N = 2048, D = 128, H = 2;
constexpr int C2 = H * D;           // 256
constexpr int M_ = B_ * N;          // 16384
constexpr int NCH = 32;             // scan chunks
constexpr int CHL = N / NCH;        // 64

__device__ __forceinline__ float lrelu(float x) { return fmaxf(x, ALPHA_SLOPE * x); }

// ---------- cvtW: W -> WcT f16, 128 blocks ----------
__global__ __launch_bounds__(256) void cvtW_kernel(
    const float* __restrict__ W00, const float* __restrict__ W01,
    const float* __restrict__ W10, const float* __restrict__ W11,
    f16* __restrict__ WcT)
{
    const int t = threadIdx.x;
    const int w = blockIdx.x;                  // [0,128)
#pragma unroll
    for (int p = 0; p < 4; ++p) {
        const int pair = w * 4 + p;            // [0,512)
        const int layer = pair >> 8, c = pair & 255;
        const float* __restrict__ W0 = layer ? W10 : W00;
        const float* __restrict__ W1 = layer ? W11 : W01;
        const float v = (c < D) ? W0[t * D + c] : W1[t * D + (c - D)];
        WcT[(size_t)layer * C2 * C2 + c * C2 + t] = (f16)v;
    }
}

// ---------- gemm_lr: 32-row tiles, 1024 threads (16 waves -> 32 waves/CU) ----------
__global__ __launch_bounds__(1024) void gemm_lr_kernel(
    const float* __restrict__ x32, const f16* __restrict__ xh,
    const f16* __restrict__ Wl,
    const float* __restrict__ b0, const float* __restrict__ b1,
    const float* __restrict__ a0, const float* __restrict__ a1,
    f16* __restrict__ h,
    float* __restrict__ l0, float* __restrict__ r0,
    float* __restrict__ l1, float* __restrict__ r1,
    const int use32)
{
    __shared__ f16 hts[32][C2 + 8];   // 16896 B: x tile, then h tile
    const int t = threadIdx.x;
    const int row0 = blockIdx.x * 32;
    if (use32) {
#pragma unroll
        for (int p = 0; p < 2; ++p) {
            const int q = p * 1024 + t;         // [0,2048) float4 units
            const int row = q >> 6, c4 = q & 63;
            const float4 v = *(const float4*)&x32[(size_t)(row0 + row) * C2 + c4 * 4];
            f16x4 o; o[0] = (f16)v.x; o[1] = (f16)v.y; o[2] = (f16)v.z; o[3] = (f16)v.w;
            *(f16x4*)&hts[row][c4 * 4] = o;
        }
    } else {
        const int q = t;                        // [0,1024) f16x8 units
        const int row = q >> 5, cc = q & 31;
        *(f16x8*)&hts[row][cc * 8] = *(const f16x8*)&xh[(size_t)(row0 + row) * C2 + cc * 8];
    }
    __syncthreads();
    const int w = t >> 6, l = t & 63;           // w in [0,16): 16-col strip per wave
    const int fm = l & 15, fk = (l >> 4) * 8;
    const int col = w * 16 + fm;
    f32x4 acc[2] = {};
#pragma unroll
    for (int ks = 0; ks < 8; ++ks) {
        f16x8 af[2], bf;
#pragma unroll
        for (int rt = 0; rt < 2; ++rt)
            af[rt] = *(const f16x8*)&hts[rt * 16 + fm][ks * 32 + fk];
        bf = *(const f16x8*)&Wl[(size_t)col * C2 + ks * 32 + fk];
#pragma unroll
        for (int rt = 0; rt < 2; ++rt)
            acc[rt] = __builtin_amdgcn_mfma_f32_16x16x32_f16(af[rt], bf, acc[rt], 0, 0, 0);
    }
    __syncthreads();   // x reads done; reuse as h tile (f16)
    {
        const float bias = (col < D) ? b0[col] : b1[col - D];
#pragma unroll
        for (int rt = 0; rt < 2; ++rt)
#pragma unroll
            for (int q = 0; q < 4; ++q) {
                const int row = rt * 16 + (l >> 4) * 4 + q;
                hts[row][col] = (f16)(acc[rt][q] + bias);
            }
    }
    __syncthreads();
    {
        const int q = t;                        // [0,1024) f16x8 units
        const int row = q >> 5, cc = q & 31;
        *(f16x8*)&h[(size_t)(row0 + row) * C2 + cc * 8] = *(const f16x8*)&hts[row][cc * 8];
    }
    // l/r: 8 threads per row (oct), rotated cols to dodge bank conflicts (t<256)
    if (t < 256) {
        const int lrow = t >> 3;
        const int oct = t & 7;
        const float* __restrict__ ab = (oct >= 4) ? a1 : a0;
        float lv = 0.f, rv = 0.f;
#pragma unroll
        for (int c4 = 0; c4 < 8; ++c4) {
            const int cc = (c4 + oct) & 7;
            const int colx = oct * 32 + cc * 4;
            const int cih = (oct & 3) * 32 + cc * 4;
            const f16x4 hf = *(const f16x4*)&hts[lrow][colx];
            const float4 alv = *(const float4*)&ab[cih];
            const float4 arv = *(const float4*)&ab[128 + cih];
            const float h0 = (float)hf[0], h1 = (float)hf[1], h2 = (float)hf[2], h3 = (float)hf[3];
            lv += h0 * alv.x + h1 * alv.y + h2 * alv.z + h3 * alv.w;
            rv += h0 * arv.x + h1 * arv.y + h2 * arv.z + h3 * arv.w;
        }
        lv += __shfl_xor(lv, 1, 64); lv += __shfl_xor(lv, 2, 64);
        rv += __shfl_xor(rv, 1, 64); rv += __shfl_xor(rv, 2, 64);
        const int grow = row0 + lrow;
        if (oct == 0) { l0[grow] = lv; r0[grow] = rv; }
        else if (oct == 4) { l1[grow] = lv; r1[grow] = rv; }
    }
}

// ---------- rank: 1024-thread blocks, 16 wave-uniform j-chunks (full occupancy) ----------
__global__ __launch_bounds__(1024) void rank_kernel(
    const float* __restrict__ r0, const float* __restrict__ r1,
    const float* __restrict__ l0, const float* __restrict__ l1,
    float* __restrict__ rs_s, int* __restrict__ perm, int* __restrict__ kout)
{
    const int bh = blockIdx.y;
    const float* __restrict__ r = ((bh & 1) ? r1 : r0) + (size_t)(bh >> 1) * N;
    const float* __restrict__ lp = ((bh & 1) ? l1 : l0) + (size_t)(bh >> 1) * N;
    __shared__ float rl[N];
    __shared__ int scnt[16][64], sk2[16][64];
    const int t = threadIdx.x;
    for (int j = t; j < N; j += 1024) rl[j] = r[j];
    __syncthreads();
    const int el = t & 63;
    const int q = t >> 6;                       // wave index: j-chunk, uniform per wave
    const int e = blockIdx.x * 64 + el;
    const float re = rl[e];
    const float thr = -lp[e];
    const int qm = blockIdx.x >> 1;             // chunk containing this block's e's (128-wide)
    int cnt = 0, k2 = 0;
    const int jlo = q * 128, jhi = jlo + 128;
    if (q < qm) {
        for (int j = jlo; j < jhi; j += 4) {
            const float4 v = *(const float4*)&rl[j];
            cnt += (v.x >= re) + (v.y >= re) + (v.z >= re) + (v.w >= re);
            k2  += (v.x >= thr) + (v.y >= thr) + (v.z >= thr) + (v.w >= thr);
        }
    } else if (q > qm) {
        for (int j = jlo; j < jhi; j += 4) {
            const float4 v = *(const float4*)&rl[j];
            cnt += (v.x > re) + (v.y > re) + (v.z > re) + (v.w > re);
            k2  += (v.x >= thr) + (v.y >= thr) + (v.z >= thr) + (v.w >= thr);
        }
    } else {
        for (int j = jlo; j < jhi; j += 4) {
            const float4 v = *(const float4*)&rl[j];
            cnt += (v.x > re) || (v.x == re && (j + 0) < e);
            cnt += (v.y > re) || (v.y == re && (j + 1) < e);
            cnt += (v.z > re) || (v.z == re && (j + 2) < e);
            cnt += (v.w > re) || (v.w == re && (j + 3) < e);
            k2  += (v.x >= thr) + (v.y >= thr) + (v.z >= thr) + (v.w >= thr);
        }
    }
    scnt[q][el] = cnt; sk2[q][el] = k2;
    __syncthreads();
    if (t < 64) {
        int c = 0, kk = 0;
#pragma unroll
        for (int qq = 0; qq < 16; ++qq) { c += scnt[qq][t]; kk += sk2[qq][t]; }
        const int eg = blockIdx.x * 64 + t;
        const size_t g = (size_t)bh * N;
        rs_s[g + c] = rl[eg];
        perm[g + c] = eg;
        kout[g + eg] = kk;
    }
}

// ---------- scanA: 1024 threads, hierarchical 4x16 j-scan (32 waves/CU) ----------
__global__ __launch_bounds__(1024) void scanA_kernel(
    const f16* __restrict__ h, const int* __restrict__ perm,
    const float* __restrict__ rs_s,
    f16* __restrict__ PA, f16* __restrict__ PB,
    float* __restrict__ SAloc, float* __restrict__ SBloc,
    float* __restrict__ totA, float* __restrict__ totB,
    float* __restrict__ stA, float* __restrict__ stB)
{
    __shared__ f16 hs[CHL][D];          // 16384 B
    __shared__ int pj[CHL];
    __shared__ float wA[CHL], wB[CHL];
    __shared__ float buf[2 * CHL];
    __shared__ float subA[4][D], subB[4][D];   // 4096 B
    const int chunk = blockIdx.x, bh = blockIdx.y;
    const int b = bh >> 1, head = bh & 1;
    const int t = threadIdx.x;
    const size_t g = (size_t)bh * N + chunk * CHL;
    const float c1 = rs_s[(size_t)bh * N];
    if (t < CHL) {
        pj[t] = perm[g + t];
        const float rr = rs_s[g + t];
        const float eA = __expf(rr - c1);
        const float eB = __expf(0.2f * (rr - c1));
        wA[t] = eA; wB[t] = eB;
        buf[t] = eA;
    } else if (t < 2 * CHL) {
        const float rr = rs_s[g + (CHL - 1 - (t - CHL))];
        buf[t] = __expf(0.2f * (rr - c1));   // reversed B: suffix via prefix
    }
    __syncthreads();
    const int li = t & (CHL - 1);
#pragma unroll
    for (int off = 1; off < CHL; off <<= 1) {
        const float v = (t < 2 * CHL && li >= off) ? buf[t - off] : 0.f;
        __syncthreads();
        if (t < 2 * CHL && li >= off) buf[t] += v;
        __syncthreads();
    }
    if (t < CHL) SAloc[g + t] = buf[t];
    else if (t < 2 * CHL) SBloc[g + (CHL - 1 - li)] = buf[t];
    if (t == CHL - 1) stA[bh * NCH + chunk] = buf[CHL - 1];
    if (t == 2 * CHL - 1) stB[bh * NCH + chunk] = buf[2 * CHL - 1];
    // gather permuted h rows (f16): 1024 f16x8 units, one per thread
    {
        const int row = t >> 4, c8 = t & 15;
        const f16* src = h + (size_t)(b * N + pj[row]) * C2 + head * D;
        *(f16x8*)&hs[row][c8 * 8] = *(const f16x8*)&src[c8 * 8];
    }
    __syncthreads();
    // hierarchical scan: s = sub-chunk (0-3), 16 j's each; u<128 -> A-scan d=u, u>=128 -> B d=u-128
    const int s = t >> 8;
    const int u = t & 255;
    const int jbase = s * 16;
    float vals[16];
    if (u < D) {
        const int d = u;
        float acc = 0.f;
#pragma unroll
        for (int jj = 0; jj < 16; ++jj) {
            acc = fmaf(wA[jbase + jj], (float)hs[jbase + jj][d], acc);
            vals[jj] = acc;
        }
        subA[s][d] = acc;
    } else {
        const int d = u - D;
        float acc = 0.f;
#pragma unroll
        for (int jj = 15; jj >= 0; --jj) {
            acc = fmaf(wB[jbase + jj], (float)hs[jbase + jj][d], acc);
            vals[jj] = acc;
        }
        subB[s][d] = acc;
    }
    __syncthreads();
    if (u < D) {
        const int d = u;
        float offA = 0.f;
#pragma unroll
        for (int ss = 0; ss < 3; ++ss) if (ss < s) offA += subA[ss][d];
#pragma unroll
        for (int jj = 0; jj < 16; ++jj)
            PA[(g + jbase + jj) * D + d] = (f16)(vals[jj] + offA);
        if (s == 3) totA[(size_t)(bh * NCH + chunk) * D + d] = offA + subA[3][d];
    } else {
        const int d = u - D;
        float offB = 0.f;
#pragma unroll
        for (int ss = 1; ss < 4; ++ss) if (ss > s) offB += subB[ss][d];
#pragma unroll
        for (int jj = 0; jj < 16; ++jj)
            PB[(g + jbase + jj) * D + d] = (f16)(vals[jj] + offB);
        if (s == 0) totB[(size_t)(bh * NCH + chunk) * D + d] = offB + subB[0][d];
    }
}

// ---------- scanOff: per-bh chunk-offset exclusive scans ----------
__global__ __launch_bounds__(256) void scanOff_kernel(
    const float* __restrict__ totA, const float* __restrict__ totB,
    const float* __restrict__ stA, const float* __restrict__ stB,
    float* __restrict__ AOff, float* __restrict__ BOffS,
    float* __restrict__ lsAg, float* __restrict__ lsBg)
{
    const int bh = blockIdx.x;
    const int t = threadIdx.x;
    const size_t base = (size_t)bh * NCH;
    if (t < D) {
        const int d = t;
        float acc = 0.f;
#pragma unroll
        for (int ch = 0; ch < NCH; ++ch) {
            const float tmp = totA[(base + ch) * D + d];
            AOff[(base + ch) * D + d] = acc;
            acc += tmp;
        }
    } else {
        const int d = t - D;
        float acc = 0.f;
#pragma unroll
        for (int ch = NCH - 1; ch >= 0; --ch) {
            const float tmp = totB[(base + ch) * D + d];
            BOffS[(base + ch) * D + d] = acc;
            acc += tmp;
        }
    }
    if (t == 0) {
        float a = 0.f;
#pragma unroll
        for (int q = 0; q < NCH; ++q) { const float tmp = stA[base + q]; lsAg[base + q] = a; a += tmp; }
    } else if (t == 64) {
        float a = 0.f;
#pragma unroll
        for (int q = NCH - 1; q >= 0; --q) { const float tmp = stB[base + q]; lsBg[base + q] = a; a += tmp; }
    }
}

// ---------- out: LDS-free streaming combine + elu ----------
__global__ __launch_bounds__(256) void out_kernel(
    const f16* __restrict__ h,
    const float* __restrict__ l0v, const float* __restrict__ l1v,
    const float* __restrict__ r0v, const float* __restrict__ r1v,
    const int* __restrict__ perm, const float* __restrict__ rs_s,
    const int* __restrict__ kout,
    const float* __restrict__ SAloc, const float* __restrict__ SBloc,
    const float* __restrict__ lsAg, const float* __restrict__ lsBg,
    const float* __restrict__ AOff, const float* __restrict__ BOffS,
    const f16* __restrict__ PA, const f16* __restrict__ PB,
    float* __restrict__ out_f32, f16* __restrict__ out_f16, const int final_layer)
{
    const int head = blockIdx.y, b = blockIdx.z;
    const int bh = b * H + head;
    const float* __restrict__ lv = (head ? l1v : l0v) + (size_t)b * N;
    const float* __restrict__ rv = (head ? r1v : r0v) + (size_t)b * N;
    const int t = threadIdx.x;
    const size_t gb = (size_t)bh * N;
    const size_t obase = (size_t)bh * NCH;

    const int i = blockIdx.x * 16 + (t >> 4);
    const int c0 = (t & 15) * 8;
    const float li = lv[i];
    const float ri = rv[i];
    const float rmx1 = rs_s[gb];
    const float rmx2 = rs_s[gb + 1];
    const int rdx = perm[gb];
    const float rmx = (i == rdx) ? rmx2 : rmx1;
    const float m = lrelu(li + rmx);
    const float alpha = __expf(li + rmx1 - m);
    const float beta = __expf(0.2f * (li + rmx1) - m);
    const float diag = __expf(lrelu(li + ri) - m);

    const int k = kout[gb + i];
    const float SAk = (k > 0) ? (lsAg[obase + ((k - 1) >> 6)] + SAloc[gb + k - 1]) : 0.f;
    const float SBk = (k < N) ? (lsBg[obase + (k >> 6)] + SBloc[gb + k]) : 0.f;
    const float Z = fmaf(alpha, SAk, beta * SBk) - diag;
    const float invZ = 1.f / Z;

    float pa[8] = {}, pb[8] = {};
    if (k > 0) {
        const int kk = k - 1, ch = kk >> 6;
        const f16x8 v = *(const f16x8*)&PA[(gb + kk) * D + c0];
        const float4 o0 = *(const float4*)&AOff[(obase + ch) * D + c0];
        const float4 o1 = *(const float4*)&AOff[(obase + ch) * D + c0 + 4];
        pa[0] = (float)v[0] + o0.x; pa[1] = (float)v[1] + o0.y;
        pa[2] = (float)v[2] + o0.z; pa[3] = (float)v[3] + o0.w;
        pa[4] = (float)v[4] + o1.x; pa[5] = (float)v[5] + o1.y;
        pa[6] = (float)v[6] + o1.z; pa[7] = (float)v[7] + o1.w;
    }
    if (k < N) {
        const int ch = k >> 6;
        const f16x8 v = *(const f16x8*)&PB[(gb + k) * D + c0];
        const float4 o0 = *(const float4*)&BOffS[(obase + ch) * D + c0];
        const float4 o1 = *(const float4*)&BOffS[(obase + ch) * D + c0 + 4];
        pb[0] = (float)v[0] + o0.x; pb[1] = (float)v[1] + o0.y;
        pb[2] = (float)v[2] + o0.z; pb[3] = (float)v[3] + o0.w;
        pb[4] = (float)v[4] + o1.x; pb[5] = (float)v[5] + o1.y;
        pb[6] = (float)v[6] + o1.z; pb[7] = (float)v[7] + o1.w;
    }

    const f16x8 hraw = *(const f16x8*)&h[(size_t)(b * N + i) * C2 + head * D + c0];
    float o[8];
#pragma unroll
    for (int q = 0; q < 8; ++q) {
        const float hv = (float)hraw[q];
        const float num = alpha * pa[q] + beta * pb[q] - diag * hv;
        float v = fmaf(num, invZ, hv);
        o[q] = v > 0.f ? v : (__expf(v) - 1.f);
    }
    const size_t oidx = (size_t)(b * N + i) * C2 + head * D + c0;
    if (final_layer) {
        *(float4*)&out_f32[oidx] = make_float4(o[0], o[1], o[2], o[3]);
        *(float4*)&out_f32[oidx + 4] = make_float4(o[4], o[5], o[6], o[7]);
    } else {
        f16x8 ov;
#pragma unroll
        for (int q = 0; q < 8; ++q) ov[q] = (f16)o[q];
        *(f16x8*)&out_f16[oidx] = ov;
    }
}

extern "C" void kernel_launch(void* const* d_in, const int* in_sizes, int n_in,
                              void* d_out, int out_size, void* d_ws, size_t ws_size,
                              hipStream_t stream)
{
    float* ws = (float*)d_ws;
    size_t off = 0;
    f16* xh = (f16*)(ws + off);   off += (size_t)M_ * C2 / 2;
    f16* WcT = (f16*)(ws + off);  off += (size_t)C2 * C2;        // 2 layers f16
    f16* h = (f16*)(ws + off);    off += (size_t)M_ * C2 / 2;
    float* l0 = ws + off;         off += (size_t)B_ * N;
    float* r0 = ws + off;         off += (size_t)B_ * N;
    float* l1 = ws + off;         off += (size_t)B_ * N;
    float* r1 = ws + off;         off += (size_t)B_ * N;
    float* rs_s = ws + off;       off += (size_t)16 * N;
    int* perm = (int*)(ws + off); off += (size_t)16 * N;
    int* kout = (int*)(ws + off); off += (size_t)16 * N;
    float* SAloc = ws + off;      off += (size_t)16 * N;
    float* SBloc = ws + off;      off += (size_t)16 * N;
    f16* PA = (f16*)(ws + off);   off += (size_t)16 * N * D / 2;
    f16* PB = (f16*)(ws + off);   off += (size_t)16 * N * D / 2;
    float* totA = ws + off;       off += (size_t)16 * NCH * D;
    float* totB = ws + off;       off += (size_t)16 * NCH * D;
    float* stA = ws + off;        off += (size_t)16 * NCH;
    float* stB = ws + off;        off += (size_t)16 * NCH;
    float* AOff = ws + off;       off += (size_t)16 * NCH * D;
    float* BOffS = ws + off;      off += (size_t)16 * NCH * D;
    float* lsAg = ws + off;       off += (size_t)16 * NCH;
    float* lsBg = ws + off;       off += (size_t)16 * NCH;

    const float* x32 = (const float*)d_in[0];

    cvtW_kernel<<<128, 256, 0, stream>>>(
        (const float*)d_in[2], (const float*)d_in[5],
        (const float*)d_in[8], (const float*)d_in[11], WcT);

    for (int layer = 0; layer < 2; ++layer) {
        const int base = 2 + layer * 6;
        const float* b0 = (const float*)d_in[base + 1];
        const float* a0 = (const float*)d_in[base + 2];
        const float* b1 = (const float*)d_in[base + 4];
        const float* a1 = (const float*)d_in[base + 5];

        gemm_lr_kernel<<<M_ / 32, 1024, 0, stream>>>(
            x32, xh, WcT + (size_t)layer * C2 * C2, b0, b1, a0, a1,
            h, l0, r0, l1, r1, layer == 0 ? 1 : 0);
        rank_kernel<<<dim3(N / 64, B_ * H), 1024, 0, stream>>>(
            r0, r1, l0, l1, rs_s, perm, kout);
        scanA_kernel<<<dim3(NCH, B_ * H), 1024, 0, stream>>>(
            h, perm, rs_s, PA, PB, SAloc, SBloc, totA, totB, stA, stB);
        scanOff_kernel<<<B_ * H, 256, 0, stream>>>(
            totA, totB, stA, stB, AOff, BOffS, lsAg, lsBg);
        out_kernel<<<dim3(N / 16, H, B_), 256, 0, stream>>>(
            h, l0, l1, r0, r1, perm, rs_s, kout, SAloc, SBloc, lsAg, lsBg,
            AOff, BOffS, PA, PB, (float*)d_out, xh, layer == 1 ? 1 : 0);
    }
}

// Round 12
// 175.977 us; speedup vs baseline: 3.2197x; 1.0306x over previous
//
#include <hip/hip_runtime.h>
#include <math.h>

#define ALPHA_SLOPE 0.2f

typedef _Float16 f16;
typedef f16 f16x4 __attribute__((ext_vector_type(4)));
typedef f16 f16x8 __attribute__((ext_vector_type(8)));
typedef float f32x4 __attribute__((ext_vector_type(4)));

constexpr int B_ = 8, N = 2048, D = 128, H = 2;
constexpr int C2 = H * D;           // 256
constexpr int M_ = B_ * N;          // 16384
constexpr int NCH = 32;             // scan chunks
constexpr int CHL = N / NCH;        // 64

__device__ __forceinline__ float lrelu(float x) { return fmaxf(x, ALPHA_SLOPE * x); }

// XCD-affinity scheme: dispatcher round-robins blockIdx over 8 XCDs (blockIdx%8=XCD,
// performance heuristic only). All phases put batch b's work at blockIdx ? b (mod 8)
// so producer->consumer reads hit the same 4MB L2 (batch working set ~3.5MB).

// ---------- cvtW: W -> WcT f16, 128 blocks (shared weights, unswizzled) ----------
__global__ __launch_bounds__(256) void cvtW_kernel(
    const float* __restrict__ W00, const float* __restrict__ W01,
    const float* __restrict__ W10, const float* __restrict__ W11,
    f16* __restrict__ WcT)
{
    const int t = threadIdx.x;
    const int w = blockIdx.x;                  // [0,128)
#pragma unroll
    for (int p = 0; p < 4; ++p) {
        const int pair = w * 4 + p;            // [0,512)
        const int layer = pair >> 8, c = pair & 255;
        const float* __restrict__ W0 = layer ? W10 : W00;
        const float* __restrict__ W1 = layer ? W11 : W01;
        const float v = (c < D) ? W0[t * D + c] : W1[t * D + (c - D)];
        WcT[(size_t)layer * C2 * C2 + c * C2 + t] = (f16)v;
    }
}

// ---------- gemm_lr: 32-row tiles, 1024 threads; batch = blk&7 (XCD affinity) ----------
__global__ __launch_bounds__(1024) void gemm_lr_kernel(
    const float* __restrict__ x32, const f16* __restrict__ xh,
    const f16* __restrict__ Wl,
    const float* __restrict__ b0, const float* __restrict__ b1,
    const float* __restrict__ a0, const float* __restrict__ a1,
    f16* __restrict__ h,
    float* __restrict__ l0, float* __restrict__ r0,
    float* __restrict__ l1, float* __restrict__ r1,
    const int use32)
{
    __shared__ f16 hts[32][C2 + 8];   // 16896 B: x tile, then h tile
    const int t = threadIdx.x;
    const int batch = blockIdx.x & 7;          // -> XCD batch
    const int slot = blockIdx.x >> 3;          // [0,64) tile within batch
    const int row0 = batch * N + slot * 32;
    if (use32) {
#pragma unroll
        for (int p = 0; p < 2; ++p) {
            const int q = p * 1024 + t;         // [0,2048) float4 units
            const int row = q >> 6, c4 = q & 63;
            const float4 v = *(const float4*)&x32[(size_t)(row0 + row) * C2 + c4 * 4];
            f16x4 o; o[0] = (f16)v.x; o[1] = (f16)v.y; o[2] = (f16)v.z; o[3] = (f16)v.w;
            *(f16x4*)&hts[row][c4 * 4] = o;
        }
    } else {
        const int q = t;                        // [0,1024) f16x8 units
        const int row = q >> 5, cc = q & 31;
        *(f16x8*)&hts[row][cc * 8] = *(const f16x8*)&xh[(size_t)(row0 + row) * C2 + cc * 8];
    }
    __syncthreads();
    const int w = t >> 6, l = t & 63;           // w in [0,16): 16-col strip per wave
    const int fm = l & 15, fk = (l >> 4) * 8;
    const int col = w * 16 + fm;
    f32x4 acc[2] = {};
#pragma unroll
    for (int ks = 0; ks < 8; ++ks) {
        f16x8 af[2], bf;
#pragma unroll
        for (int rt = 0; rt < 2; ++rt)
            af[rt] = *(const f16x8*)&hts[rt * 16 + fm][ks * 32 + fk];
        bf = *(const f16x8*)&Wl[(size_t)col * C2 + ks * 32 + fk];
#pragma unroll
        for (int rt = 0; rt < 2; ++rt)
            acc[rt] = __builtin_amdgcn_mfma_f32_16x16x32_f16(af[rt], bf, acc[rt], 0, 0, 0);
    }
    __syncthreads();   // x reads done; reuse as h tile (f16)
    {
        const float bias = (col < D) ? b0[col] : b1[col - D];
#pragma unroll
        for (int rt = 0; rt < 2; ++rt)
#pragma unroll
            for (int q = 0; q < 4; ++q) {
                const int row = rt * 16 + (l >> 4) * 4 + q;
                hts[row][col] = (f16)(acc[rt][q] + bias);
            }
    }
    __syncthreads();
    {
        const int q = t;                        // [0,1024) f16x8 units
        const int row = q >> 5, cc = q & 31;
        *(f16x8*)&h[(size_t)(row0 + row) * C2 + cc * 8] = *(const f16x8*)&hts[row][cc * 8];
    }
    // l/r: 8 threads per row (oct), rotated cols to dodge bank conflicts (t<256)
    if (t < 256) {
        const int lrow = t >> 3;
        const int oct = t & 7;
        const float* __restrict__ ab = (oct >= 4) ? a1 : a0;
        float lv = 0.f, rv = 0.f;
#pragma unroll
        for (int c4 = 0; c4 < 8; ++c4) {
            const int cc = (c4 + oct) & 7;
            const int colx = oct * 32 + cc * 4;
            const int cih = (oct & 3) * 32 + cc * 4;
            const f16x4 hf = *(const f16x4*)&hts[lrow][colx];
            const float4 alv = *(const float4*)&ab[cih];
            const float4 arv = *(const float4*)&ab[128 + cih];
            const float h0 = (float)hf[0], h1 = (float)hf[1], h2 = (float)hf[2], h3 = (float)hf[3];
            lv += h0 * alv.x + h1 * alv.y + h2 * alv.z + h3 * alv.w;
            rv += h0 * arv.x + h1 * arv.y + h2 * arv.z + h3 * arv.w;
        }
        lv += __shfl_xor(lv, 1, 64); lv += __shfl_xor(lv, 2, 64);
        rv += __shfl_xor(rv, 1, 64); rv += __shfl_xor(rv, 2, 64);
        const int grow = row0 + lrow;
        if (oct == 0) { l0[grow] = lv; r0[grow] = rv; }
        else if (oct == 4) { l1[grow] = lv; r1[grow] = rv; }
    }
}

// ---------- rank: 1024 threads, 16 wave-uniform j-chunks; batch = blk&7 ----------
__global__ __launch_bounds__(1024) void rank_kernel(
    const float* __restrict__ r0, const float* __restrict__ r1,
    const float* __restrict__ l0, const float* __restrict__ l1,
    float* __restrict__ rs_s, int* __restrict__ perm, int* __restrict__ kout)
{
    const int batch = blockIdx.x & 7;
    const int rest = blockIdx.x >> 3;          // [0,64)
    const int head = rest & 1;
    const int chunk = rest >> 1;               // [0,32): e-chunk of 64
    const int bh = batch * 2 + head;
    const float* __restrict__ r = (head ? r1 : r0) + (size_t)batch * N;
    const float* __restrict__ lp = (head ? l1 : l0) + (size_t)batch * N;
    __shared__ float rl[N];
    __shared__ int scnt[16][64], sk2[16][64];
    const int t = threadIdx.x;
    for (int j = t; j < N; j += 1024) rl[j] = r[j];
    __syncthreads();
    const int el = t & 63;
    const int q = t >> 6;                       // wave index: j-chunk, uniform per wave
    const int e = chunk * 64 + el;
    const float re = rl[e];
    const float thr = -lp[e];
    const int qm = chunk >> 1;                  // 128-wide chunk containing this block's e's
    int cnt = 0, k2 = 0;
    const int jlo = q * 128, jhi = jlo + 128;
    if (q < qm) {
        for (int j = jlo; j < jhi; j += 4) {
            const float4 v = *(const float4*)&rl[j];
            cnt += (v.x >= re) + (v.y >= re) + (v.z >= re) + (v.w >= re);
            k2  += (v.x >= thr) + (v.y >= thr) + (v.z >= thr) + (v.w >= thr);
        }
    } else if (q > qm) {
        for (int j = jlo; j < jhi; j += 4) {
            const float4 v = *(const float4*)&rl[j];
            cnt += (v.x > re) + (v.y > re) + (v.z > re) + (v.w > re);
            k2  += (v.x >= thr) + (v.y >= thr) + (v.z >= thr) + (v.w >= thr);
        }
    } else {
        for (int j = jlo; j < jhi; j += 4) {
            const float4 v = *(const float4*)&rl[j];
            cnt += (v.x > re) || (v.x == re && (j + 0) < e);
            cnt += (v.y > re) || (v.y == re && (j + 1) < e);
            cnt += (v.z > re) || (v.z == re && (j + 2) < e);
            cnt += (v.w > re) || (v.w == re && (j + 3) < e);
            k2  += (v.x >= thr) + (v.y >= thr) + (v.z >= thr) + (v.w >= thr);
        }
    }
    scnt[q][el] = cnt; sk2[q][el] = k2;
    __syncthreads();
    if (t < 64) {
        int c = 0, kk = 0;
#pragma unroll
        for (int qq = 0; qq < 16; ++qq) { c += scnt[qq][t]; kk += sk2[qq][t]; }
        const int eg = chunk * 64 + t;
        const size_t g = (size_t)bh * N;
        rs_s[g + c] = rl[eg];
        perm[g + c] = eg;
        kout[g + eg] = kk;
    }
}

// ---------- scanA: 1024 threads, hierarchical 4x16 j-scan; batch = blk&7 ----------
__global__ __launch_bounds__(1024) void scanA_kernel(
    const f16* __restrict__ h, const int* __restrict__ perm,
    const float* __restrict__ rs_s,
    f16* __restrict__ PA, f16* __restrict__ PB,
    float* __restrict__ SAloc, float* __restrict__ SBloc,
    float* __restrict__ totA, float* __restrict__ totB,
    float* __restrict__ stA, float* __restrict__ stB)
{
    __shared__ f16 hs[CHL][D];          // 16384 B
    __shared__ int pj[CHL];
    __shared__ float wA[CHL], wB[CHL];
    __shared__ float buf[2 * CHL];
    __shared__ float subA[4][D], subB[4][D];   // 4096 B
    const int batch = blockIdx.x & 7;
    const int rest = blockIdx.x >> 3;          // [0,64)
    const int head = rest & 1;
    const int chunk = rest >> 1;               // [0,32)
    const int bh = batch * 2 + head;
    const int b = batch;
    const int t = threadIdx.x;
    const size_t g = (size_t)bh * N + chunk * CHL;
    const float c1 = rs_s[(size_t)bh * N];
    if (t < CHL) {
        pj[t] = perm[g + t];
        const float rr = rs_s[g + t];
        const float eA = __expf(rr - c1);
        const float eB = __expf(0.2f * (rr - c1));
        wA[t] = eA; wB[t] = eB;
        buf[t] = eA;
    } else if (t < 2 * CHL) {
        const float rr = rs_s[g + (CHL - 1 - (t - CHL))];
        buf[t] = __expf(0.2f * (rr - c1));   // reversed B: suffix via prefix
    }
    __syncthreads();
    const int li = t & (CHL - 1);
#pragma unroll
    for (int off = 1; off < CHL; off <<= 1) {
        const float v = (t < 2 * CHL && li >= off) ? buf[t - off] : 0.f;
        __syncthreads();
        if (t < 2 * CHL && li >= off) buf[t] += v;
        __syncthreads();
    }
    if (t < CHL) SAloc[g + t] = buf[t];
    else if (t < 2 * CHL) SBloc[g + (CHL - 1 - li)] = buf[t];
    if (t == CHL - 1) stA[bh * NCH + chunk] = buf[CHL - 1];
    if (t == 2 * CHL - 1) stB[bh * NCH + chunk] = buf[2 * CHL - 1];
    // gather permuted h rows (f16): 1024 f16x8 units, one per thread
    {
        const int row = t >> 4, c8 = t & 15;
        const f16* src = h + (size_t)(b * N + pj[row]) * C2 + head * D;
        *(f16x8*)&hs[row][c8 * 8] = *(const f16x8*)&src[c8 * 8];
    }
    __syncthreads();
    // hierarchical scan: s = sub-chunk (0-3), 16 j's each; u<128 -> A-scan d=u, u>=128 -> B
    const int s = t >> 8;
    const int u = t & 255;
    const int jbase = s * 16;
    float vals[16];
    if (u < D) {
        const int d = u;
        float acc = 0.f;
#pragma unroll
        for (int jj = 0; jj < 16; ++jj) {
            acc = fmaf(wA[jbase + jj], (float)hs[jbase + jj][d], acc);
            vals[jj] = acc;
        }
        subA[s][d] = acc;
    } else {
        const int d = u - D;
        float acc = 0.f;
#pragma unroll
        for (int jj = 15; jj >= 0; --jj) {
            acc = fmaf(wB[jbase + jj], (float)hs[jbase + jj][d], acc);
            vals[jj] = acc;
        }
        subB[s][d] = acc;
    }
    __syncthreads();
    if (u < D) {
        const int d = u;
        float offA = 0.f;
#pragma unroll
        for (int ss = 0; ss < 3; ++ss) if (ss < s) offA += subA[ss][d];
#pragma unroll
        for (int jj = 0; jj < 16; ++jj)
            PA[(g + jbase + jj) * D + d] = (f16)(vals[jj] + offA);
        if (s == 3) totA[(size_t)(bh * NCH + chunk) * D + d] = offA + subA[3][d];
    } else {
        const int d = u - D;
        float offB = 0.f;
#pragma unroll
        for (int ss = 1; ss < 4; ++ss) if (ss > s) offB += subB[ss][d];
#pragma unroll
        for (int jj = 0; jj < 16; ++jj)
            PB[(g + jbase + jj) * D + d] = (f16)(vals[jj] + offB);
        if (s == 0) totB[(size_t)(bh * NCH + chunk) * D + d] = offB + subB[0][d];
    }
}

// ---------- scanOff: per-bh chunk-offset exclusive scans; batch = blk&7 ----------
__global__ __launch_bounds__(256) void scanOff_kernel(
    const float* __restrict__ totA, const float* __restrict__ totB,
    const float* __restrict__ stA, const float* __restrict__ stB,
    float* __restrict__ AOff, float* __restrict__ BOffS,
    float* __restrict__ lsAg, float* __restrict__ lsBg)
{
    const int batch = blockIdx.x & 7;
    const int head = blockIdx.x >> 3;          // {0,1}
    const int bh = batch * 2 + head;
    const int t = threadIdx.x;
    const size_t base = (size_t)bh * NCH;
    if (t < D) {
        const int d = t;
        float acc = 0.f;
#pragma unroll
        for (int ch = 0; ch < NCH; ++ch) {
            const float tmp = totA[(base + ch) * D + d];
            AOff[(base + ch) * D + d] = acc;
            acc += tmp;
        }
    } else {
        const int d = t - D;
        float acc = 0.f;
#pragma unroll
        for (int ch = NCH - 1; ch >= 0; --ch) {
            const float tmp = totB[(base + ch) * D + d];
            BOffS[(base + ch) * D + d] = acc;
            acc += tmp;
        }
    }
    if (t == 0) {
        float a = 0.f;
#pragma unroll
        for (int q = 0; q < NCH; ++q) { const float tmp = stA[base + q]; lsAg[base + q] = a; a += tmp; }
    } else if (t == 64) {
        float a = 0.f;
#pragma unroll
        for (int q = NCH - 1; q >= 0; --q) { const float tmp = stB[base + q]; lsBg[base + q] = a; a += tmp; }
    }
}

// ---------- out: LDS-free streaming combine + elu; batch = blk&7 ----------
__global__ __launch_bounds__(256) void out_kernel(
    const f16* __restrict__ h,
    const float* __restrict__ l0v, const float* __restrict__ l1v,
    const float* __restrict__ r0v, const float* __restrict__ r1v,
    const int* __restrict__ perm, const float* __restrict__ rs_s,
    const int* __restrict__ kout,
    const float* __restrict__ SAloc, const float* __restrict__ SBloc,
    const float* __restrict__ lsAg, const float* __restrict__ lsBg,
    const float* __restrict__ AOff, const float* __restrict__ BOffS,
    const f16* __restrict__ PA, const f16* __restrict__ PB,
    float* __restrict__ out_f32, f16* __restrict__ out_f16, const int final_layer)
{
    const int batch = blockIdx.x & 7;
    const int rest = blockIdx.x >> 3;          // [0,256)
    const int head = rest & 1;
    const int ib = rest >> 1;                  // [0,128): 16-row group
    const int b = batch;
    const int bh = b * H + head;
    const float* __restrict__ lv = (head ? l1v : l0v) + (size_t)b * N;
    const float* __restrict__ rv = (head ? r1v : r0v) + (size_t)b * N;
    const int t = threadIdx.x;
    const size_t gb = (size_t)bh * N;
    const size_t obase = (size_t)bh * NCH;

    const int i = ib * 16 + (t >> 4);
    const int c0 = (t & 15) * 8;
    const float li = lv[i];
    const float ri = rv[i];
    const float rmx1 = rs_s[gb];
    const float rmx2 = rs_s[gb + 1];
    const int rdx = perm[gb];
    const float rmx = (i == rdx) ? rmx2 : rmx1;
    const float m = lrelu(li + rmx);
    const float alpha = __expf(li + rmx1 - m);
    const float beta = __expf(0.2f * (li + rmx1) - m);
    const float diag = __expf(lrelu(li + ri) - m);

    const int k = kout[gb + i];
    const float SAk = (k > 0) ? (lsAg[obase + ((k - 1) >> 6)] + SAloc[gb + k - 1]) : 0.f;
    const float SBk = (k < N) ? (lsBg[obase + (k >> 6)] + SBloc[gb + k]) : 0.f;
    const float Z = fmaf(alpha, SAk, beta * SBk) - diag;
    const float invZ = 1.f / Z;

    float pa[8] = {}, pb[8] = {};
    if (k > 0) {
        const int kk = k - 1, ch = kk >> 6;
        const f16x8 v = *(const f16x8*)&PA[(gb + kk) * D + c0];
        const float4 o0 = *(const float4*)&AOff[(obase + ch) * D + c0];
        const float4 o1 = *(const float4*)&AOff[(obase + ch) * D + c0 + 4];
        pa[0] = (float)v[0] + o0.x; pa[1] = (float)v[1] + o0.y;
        pa[2] = (float)v[2] + o0.z; pa[3] = (float)v[3] + o0.w;
        pa[4] = (float)v[4] + o1.x; pa[5] = (float)v[5] + o1.y;
        pa[6] = (float)v[6] + o1.z; pa[7] = (float)v[7] + o1.w;
    }
    if (k < N) {
        const int ch = k >> 6;
        const f16x8 v = *(const f16x8*)&PB[(gb + k) * D + c0];
        const float4 o0 = *(const float4*)&BOffS[(obase + ch) * D + c0];
        const float4 o1 = *(const float4*)&BOffS[(obase + ch) * D + c0 + 4];
        pb[0] = (float)v[0] + o0.x; pb[1] = (float)v[1] + o0.y;
        pb[2] = (float)v[2] + o0.z; pb[3] = (float)v[3] + o0.w;
        pb[4] = (float)v[4] + o1.x; pb[5] = (float)v[5] + o1.y;
        pb[6] = (float)v[6] + o1.z; pb[7] = (float)v[7] + o1.w;
    }

    const f16x8 hraw = *(const f16x8*)&h[(size_t)(b * N + i) * C2 + head * D + c0];
    float o[8];
#pragma unroll
    for (int q = 0; q < 8; ++q) {
        const float hv = (float)hraw[q];
        const float num = alpha * pa[q] + beta * pb[q] - diag * hv;
        float v = fmaf(num, invZ, hv);
        o[q] = v > 0.f ? v : (__expf(v) - 1.f);
    }
    const size_t oidx = (size_t)(b * N + i) * C2 + head * D + c0;
    if (final_layer) {
        *(float4*)&out_f32[oidx] = make_float4(o[0], o[1], o[2], o[3]);
        *(float4*)&out_f32[oidx + 4] = make_float4(o[4], o[5], o[6], o[7]);
    } else {
        f16x8 ov;
#pragma unroll
        for (int q = 0; q < 8; ++q) ov[q] = (f16)o[q];
        *(f16x8*)&out_f16[oidx] = ov;
    }
}

extern "C" void kernel_launch(void* const* d_in, const int* in_sizes, int n_in,
                              void* d_out, int out_size, void* d_ws, size_t ws_size,
                              hipStream_t stream)
{
    float* ws = (float*)d_ws;
    size_t off = 0;
    f16* xh = (f16*)(ws + off);   off += (size_t)M_ * C2 / 2;
    f16* WcT = (f16*)(ws + off);  off += (size_t)C2 * C2;        // 2 layers f16
    f16* h = (f16*)(ws + off);    off += (size_t)M_ * C2 / 2;
    float* l0 = ws + off;         off += (size_t)B_ * N;
    float* r0 = ws + off;         off += (size_t)B_ * N;
    float* l1 = ws + off;         off += (size_t)B_ * N;
    float* r1 = ws + off;         off += (size_t)B_ * N;
    float* rs_s = ws + off;       off += (size_t)16 * N;
    int* perm = (int*)(ws + off); off += (size_t)16 * N;
    int* kout = (int*)(ws + off); off += (size_t)16 * N;
    float* SAloc = ws + off;      off += (size_t)16 * N;
    float* SBloc = ws + off;      off += (size_t)16 * N;
    f16* PA = (f16*)(ws + off);   off += (size_t)16 * N * D / 2;
    f16* PB = (f16*)(ws + off);   off += (size_t)16 * N * D / 2;
    float* totA = ws + off;       off += (size_t)16 * NCH * D;
    float* totB = ws + off;       off += (size_t)16 * NCH * D;
    float* stA = ws + off;        off += (size_t)16 * NCH;
    float* stB = ws + off;        off += (size_t)16 * NCH;
    float* AOff = ws + off;       off += (size_t)16 * NCH * D;
    float* BOffS = ws + off;      off += (size_t)16 * NCH * D;
    float* lsAg = ws + off;       off += (size_t)16 * NCH;
    float* lsBg = ws + off;       off += (size_t)16 * NCH;

    const float* x32 = (const float*)d_in[0];

    cvtW_kernel<<<128, 256, 0, stream>>>(
        (const float*)d_in[2], (const float*)d_in[5],
        (const float*)d_in[8], (const float*)d_in[11], WcT);

    for (int layer = 0; layer < 2; ++layer) {
        const int base = 2 + layer * 6;
        const float* b0 = (const float*)d_in[base + 1];
        const float* a0 = (const float*)d_in[base + 2];
        const float* b1 = (const float*)d_in[base + 4];
        const float* a1 = (const float*)d_in[base + 5];

        gemm_lr_kernel<<<M_ / 32, 1024, 0, stream>>>(
            x32, xh, WcT + (size_t)layer * C2 * C2, b0, b1, a0, a1,
            h, l0, r0, l1, r1, layer == 0 ? 1 : 0);
        rank_kernel<<<512, 1024, 0, stream>>>(
            r0, r1, l0, l1, rs_s, perm, kout);
        scanA_kernel<<<512, 1024, 0, stream>>>(
            h, perm, rs_s, PA, PB, SAloc, SBloc, totA, totB, stA, stB);
        scanOff_kernel<<<B_ * H, 256, 0, stream>>>(
            totA, totB, stA, stB, AOff, BOffS, lsAg, lsBg);
        out_kernel<<<2048, 256, 0, stream>>>(
            h, l0, l1, r0, r1, perm, rs_s, kout, SAloc, SBloc, lsAg, lsBg,
            AOff, BOffS, PA, PB, (float*)d_out, xh, layer == 1 ? 1 : 0);
    }
}